// Round 1
// baseline (539.934 us; speedup 1.0000x reference)
//
#include <hip/hip_runtime.h>
#include <hip/hip_bf16.h>

#define HDIM 128
#define RS 136  // LDS hidden row stride in bf16 elements (128 + 8 pad)

typedef __attribute__((ext_vector_type(8))) short short8;
typedef __attribute__((ext_vector_type(4))) float floatv4;

__device__ __forceinline__ unsigned short f2bf(float f) {
  union { float f; unsigned u; } x; x.f = f;
  unsigned r = x.u + 0x7fffu + ((x.u >> 16) & 1u);  // RNE
  return (unsigned short)(r >> 16);
}
__device__ __forceinline__ float blo(unsigned u) { return __uint_as_float(u << 16); }
__device__ __forceinline__ float bhi(unsigned u) { return __uint_as_float(u & 0xffff0000u); }

// dot of 8 bf16 weights (16B-aligned) with 8 fp32 values
__device__ __forceinline__ float dot8(const unsigned short* w, const float* v) {
  uint4 u = *(const uint4*)w;
  return blo(u.x) * v[0] + bhi(u.x) * v[1] + blo(u.y) * v[2] + bhi(u.y) * v[3] +
         blo(u.z) * v[4] + bhi(u.z) * v[5] + blo(u.w) * v[6] + bhi(u.w) * v[7];
}

// Exclusive scan of seq_len -> offs (ragged-safe), single block of 256 threads.
__global__ void scan_kernel(const int* __restrict__ seq, int* __restrict__ offs, int B) {
  __shared__ int part[256];
  int tid = threadIdx.x;
  int chunk = (B + 255) >> 8;
  int beg = tid * chunk, end = min(beg + chunk, B);
  int s = 0;
  for (int i = beg; i < end; ++i) s += seq[i];
  part[tid] = s;
  __syncthreads();
  for (int d = 1; d < 256; d <<= 1) {
    int v = (tid >= d) ? part[tid - d] : 0;
    __syncthreads();
    part[tid] += v;
    __syncthreads();
  }
  int run = (tid == 0) ? 0 : part[tid - 1];
  for (int i = beg; i < end; ++i) { offs[i] = run; run += seq[i]; }
}

// Convert W1[128x128], W2[128x128], W3[128x256] fp32 -> bf16 in workspace.
__global__ void convert_kernel(const float* __restrict__ W1, const float* __restrict__ W2,
                               const float* __restrict__ W3,
                               unsigned short* __restrict__ w1b, unsigned short* __restrict__ w2b,
                               unsigned short* __restrict__ w3b) {
  int i = blockIdx.x * blockDim.x + threadIdx.x;
  if (i < 16384) { w1b[i] = f2bf(W1[i]); w2b[i] = f2bf(W2[i]); }
  if (i < 32768) { w3b[i] = f2bf(W3[i]); }
}

// One block per session. 256 threads = 4 waves.
__global__ __launch_bounds__(256) void session_kernel(
    const float* __restrict__ intra, const float* __restrict__ inter,
    const unsigned short* __restrict__ w1b, const float* __restrict__ b1,
    const unsigned short* __restrict__ w2b, const float* __restrict__ b2,
    const float* __restrict__ qw, const float* __restrict__ qb,
    const unsigned short* __restrict__ w3b, const float* __restrict__ b3,
    const int* __restrict__ seq, const int* __restrict__ offs,
    float* __restrict__ out) {
  __shared__ unsigned short hbf[64 * RS];       // bf16 hidden tile, zero-padded
  __shared__ float vn[HDIM], cvec[HDIM], qv[HDIM], sg[HDIM];
  __shared__ float alphaAcc[64];
  __shared__ float sgpart[2][HDIM];

  const int b = blockIdx.x;
  const int tid = threadIdx.x;
  int n = seq[b];
  const int start = offs[b];
  if (n > 64) n = 64;  // dataset: L == 50

  // v_n (fp32) + q into LDS; init alpha accumulators with q_b
  {
    int last = start + n - 1;
    if (last < 0) last = 0;
    if (tid < HDIM) {
      size_t base = (size_t)last * HDIM + tid;
      vn[tid] = fmaxf(intra[base], inter[base]);
      qv[tid] = qw[tid];
    }
    if (tid < 64) alphaAcc[tid] = qb[0];
  }

  // Stage hidden = max(intra, inter) as bf16 into LDS, tokens >= n zero-filled.
  // Coalesced float4 loads: 8 iters x 256 threads x 4 elems = 64x128.
  for (int it = 0; it < 8; ++it) {
    int e = (it << 10) + (tid << 2);
    int t = e >> 7, j = e & 127;
    float r0 = 0.f, r1 = 0.f, r2 = 0.f, r3 = 0.f;
    if (t < n) {
      const float4 a = *(const float4*)(intra + (size_t)(start + t) * HDIM + j);
      const float4 c = *(const float4*)(inter + (size_t)(start + t) * HDIM + j);
      r0 = fmaxf(a.x, c.x); r1 = fmaxf(a.y, c.y);
      r2 = fmaxf(a.z, c.z); r3 = fmaxf(a.w, c.w);
    }
    ushort4 p; p.x = f2bf(r0); p.y = f2bf(r1); p.z = f2bf(r2); p.w = f2bf(r3);
    *(ushort4*)&hbf[t * RS + j] = p;
  }
  __syncthreads();

  // c = W1 @ v_n + b1 + b2 : 2 threads per output row, 64 MACs each.
  {
    int j = tid >> 1, h = tid & 1;
    const unsigned short* wr = w1b + j * HDIM + (h << 6);
    const float* v = vn + (h << 6);
    float s = 0.f;
    #pragma unroll
    for (int i = 0; i < 64; i += 8) s += dot8(wr + i, v + i);
    s += __shfl_xor(s, 1, 64);
    if (h == 0) cvec[j] = s + b1[j] + b2[j];
  }

  // W2 B-fragments resident in registers. Wave wid owns output cols [wid*32, wid*32+32).
  // B[k][n] = W2[n][k]; lane holds n = nbase+nt*16+lcol, k = kt*32 + quad*8 + j.
  const int lane = tid & 63, wid = tid >> 6;
  const int quad = lane >> 4, lcol = lane & 15;
  const int nbase = wid << 5;
  short8 bfrag[2][4];
  #pragma unroll
  for (int nt = 0; nt < 2; ++nt) {
    int nn = nbase + (nt << 4) + lcol;
    #pragma unroll
    for (int kt = 0; kt < 4; ++kt)
      bfrag[nt][kt] = *(const short8*)(w2b + nn * HDIM + (kt << 5) + (quad << 3));
  }
  __syncthreads();  // cvec ready; hbf already ready

  // D = hidden @ W2^T via MFMA 16x16x32 bf16; fused sigmoid + q-dot -> alphaAcc.
  #pragma unroll
  for (int mt = 0; mt < 4; ++mt) {
    floatv4 acc0 = {0.f, 0.f, 0.f, 0.f}, acc1 = {0.f, 0.f, 0.f, 0.f};
    const unsigned short* arow = &hbf[((mt << 4) + lcol) * RS + (quad << 3)];
    #pragma unroll
    for (int kt = 0; kt < 4; ++kt) {
      short8 af = *(const short8*)(arow + (kt << 5));
      acc0 = __builtin_amdgcn_mfma_f32_16x16x32_bf16(af, bfrag[0][kt], acc0, 0, 0, 0);
      acc1 = __builtin_amdgcn_mfma_f32_16x16x32_bf16(af, bfrag[1][kt], acc1, 0, 0, 0);
    }
    // C/D: lane holds D[m = quad*4 + r][n = nbase + nt*16 + lcol]
    float c0 = cvec[nbase + lcol], c1 = cvec[nbase + 16 + lcol];
    float q0 = qv[nbase + lcol], q1 = qv[nbase + 16 + lcol];
    #pragma unroll
    for (int r = 0; r < 4; ++r) {
      float v = q0 / (1.f + __expf(-(c0 + acc0[r])))
              + q1 / (1.f + __expf(-(c1 + acc1[r])));
      v += __shfl_xor(v, 1, 64);
      v += __shfl_xor(v, 2, 64);
      v += __shfl_xor(v, 4, 64);
      v += __shfl_xor(v, 8, 64);
      if (lcol == 0) atomicAdd(&alphaAcc[(mt << 4) + (quad << 2) + r], v);
    }
  }
  __syncthreads();

  // s_g[j] = sum_t alpha_t * hidden[t][j]  (two token-halves in parallel)
  {
    int j = tid & 127, h = tid >> 7;
    int t0 = h << 5, t1 = min(n, t0 + 32);
    float acc = 0.f;
    for (int t = t0; t < t1; ++t)
      acc += alphaAcc[t] * __uint_as_float((unsigned)hbf[t * RS + j] << 16);
    sgpart[h][j] = acc;
  }
  __syncthreads();
  if (tid < HDIM) sg[tid] = sgpart[0][tid] + sgpart[1][tid];
  __syncthreads();

  // h_s = [v_n, s_g] @ W3^T + b3 : 2 threads per output row (h=0 -> v_n, h=1 -> s_g)
  {
    int i = tid >> 1, h = tid & 1;
    const unsigned short* wr = w3b + i * 256 + (h << 7);
    const float* src = h ? sg : vn;
    float s = 0.f;
    #pragma unroll
    for (int k = 0; k < HDIM; k += 8) s += dot8(wr + k, src + k);
    s += __shfl_xor(s, 1, 64);
    if (h == 0) out[(size_t)b * HDIM + i] = s + b3[i];
  }
}

extern "C" void kernel_launch(void* const* d_in, const int* in_sizes, int n_in,
                              void* d_out, int out_size, void* d_ws, size_t ws_size,
                              hipStream_t stream) {
  const float* intra = (const float*)d_in[0];
  const float* inter = (const float*)d_in[1];
  const float* W1 = (const float*)d_in[2];
  const float* b1 = (const float*)d_in[3];
  const float* W2 = (const float*)d_in[4];
  const float* b2 = (const float*)d_in[5];
  const float* qw = (const float*)d_in[6];
  const float* qb = (const float*)d_in[7];
  const float* W3 = (const float*)d_in[8];
  const float* b3 = (const float*)d_in[9];
  const int* seq = (const int*)d_in[10];
  const int B = in_sizes[10];
  float* out = (float*)d_out;

  char* ws = (char*)d_ws;
  size_t o1 = (((size_t)B * 4) + 255) & ~(size_t)255;  // after offsets
  int* offs = (int*)ws;
  unsigned short* w1b = (unsigned short*)(ws + o1);            // 32 KB
  unsigned short* w2b = (unsigned short*)(ws + o1 + 32768);    // 32 KB
  unsigned short* w3b = (unsigned short*)(ws + o1 + 65536);    // 64 KB

  hipLaunchKernelGGL(scan_kernel, dim3(1), dim3(256), 0, stream, seq, offs, B);
  hipLaunchKernelGGL(convert_kernel, dim3(128), dim3(256), 0, stream, W1, W2, W3, w1b, w2b, w3b);
  hipLaunchKernelGGL(session_kernel, dim3(B), dim3(256), 0, stream,
                     intra, inter, w1b, b1, w2b, b2, qw, qb, w3b, b3, seq, offs, out);
}

// Round 2
// 507.645 us; speedup vs baseline: 1.0636x; 1.0636x over previous
//
#include <hip/hip_runtime.h>
#include <hip/hip_bf16.h>

#define HDIM 128
#define RS 136  // LDS hidden row stride in bf16 elements (128 + 8 pad)

typedef __attribute__((ext_vector_type(8))) short short8;
typedef __attribute__((ext_vector_type(4))) float floatv4;

static __device__ __forceinline__ unsigned short f2bf(float f) {
  union { float f; unsigned u; } x; x.f = f;
  unsigned r = x.u + 0x7fffu + ((x.u >> 16) & 1u);  // RNE
  return (unsigned short)(r >> 16);
}
static __device__ __forceinline__ float blo(unsigned u) { return __uint_as_float(u << 16); }
static __device__ __forceinline__ float bhi(unsigned u) { return __uint_as_float(u & 0xffff0000u); }

// Merged prep: block 0 scans seq_len -> offs; blocks 1..128 convert weights to bf16.
__global__ void prep_kernel(const int* __restrict__ seq, int* __restrict__ offs, int B,
                            const float* __restrict__ W1, const float* __restrict__ W2,
                            const float* __restrict__ W3,
                            unsigned short* __restrict__ w1b, unsigned short* __restrict__ w2b,
                            unsigned short* __restrict__ w3b) {
  if (blockIdx.x == 0) {
    __shared__ int part[256];
    int tid = threadIdx.x;
    int chunk = (B + 255) >> 8;
    int beg = tid * chunk, end = min(beg + chunk, B);
    int s = 0;
    for (int i = beg; i < end; ++i) s += seq[i];
    part[tid] = s;
    __syncthreads();
    for (int d = 1; d < 256; d <<= 1) {
      int v = (tid >= d) ? part[tid - d] : 0;
      __syncthreads();
      part[tid] += v;
      __syncthreads();
    }
    int run = (tid == 0) ? 0 : part[tid - 1];
    for (int i = beg; i < end; ++i) { offs[i] = run; run += seq[i]; }
  } else {
    int i = (blockIdx.x - 1) * 256 + threadIdx.x;
    if (i < 16384) { w1b[i] = f2bf(W1[i]); w2b[i] = f2bf(W2[i]); }
    if (i < 32768) { w3b[i] = f2bf(W3[i]); }
  }
}

// One block per session. 256 threads = 4 waves.
__global__ __launch_bounds__(256) void session_kernel(
    const float* __restrict__ intra, const float* __restrict__ inter,
    const unsigned short* __restrict__ w1b, const float* __restrict__ b1,
    const unsigned short* __restrict__ w2b, const float* __restrict__ b2,
    const float* __restrict__ qw, const float* __restrict__ qb,
    const unsigned short* __restrict__ w3b, const float* __restrict__ b3,
    const int* __restrict__ seq, const int* __restrict__ offs,
    float* __restrict__ out) {
  __shared__ unsigned short hbf[64 * RS];   // bf16 hidden tile, zero-padded (17408 B)
  __shared__ unsigned short vnb[HDIM];      // bf16 v_n
  __shared__ unsigned short sgb[HDIM];      // bf16 s_g
  __shared__ float alphaAcc[64];
  __shared__ float sgpart[4][HDIM];

  const int b = blockIdx.x;
  const int tid = threadIdx.x;
  const int lane = tid & 63, wid = tid >> 6;
  const int quad = lane >> 4, lcol = lane & 15;
  const int nbase = wid << 5;
  const int n0 = nbase + lcol, n1 = n0 + 16;  // this lane's two output columns

  int n = seq[b];
  const int start = offs[b];
  if (n > 64) n = 64;  // dataset: L == 50

  // ---- Phase A: v_n (bf16), alpha init, stage hidden tile, load W2 frags ----
  if (tid < HDIM) {
    int last = start + n - 1;
    if (last < 0) last = 0;
    size_t base = (size_t)last * HDIM + tid;
    vnb[tid] = f2bf(fmaxf(intra[base], inter[base]));
  }
  if (tid < 64) alphaAcc[tid] = qb[0];

  // hidden = max(intra, inter) -> bf16 LDS; rows >= n zero-filled.
  {
    const float4* pa = (const float4*)(intra + (size_t)start * HDIM);
    const float4* pb = (const float4*)(inter + (size_t)start * HDIM);
    #pragma unroll
    for (int it = 0; it < 8; ++it) {
      int idx = (it << 8) + tid;       // float4 index; linear over 64x128 tile
      int t = idx >> 5, j4 = idx & 31;
      float4 r; r.x = 0.f; r.y = 0.f; r.z = 0.f; r.w = 0.f;
      if (t < n) {
        float4 a = pa[idx], c = pb[idx];
        r.x = fmaxf(a.x, c.x); r.y = fmaxf(a.y, c.y);
        r.z = fmaxf(a.z, c.z); r.w = fmaxf(a.w, c.w);
      }
      union { __hip_bfloat162 b; unsigned u; } p01, p23;
      p01.b = __float22bfloat162_rn(make_float2(r.x, r.y));
      p23.b = __float22bfloat162_rn(make_float2(r.z, r.w));
      uint2 st; st.x = p01.u; st.y = p23.u;
      *(uint2*)&hbf[t * RS + (j4 << 2)] = st;
    }
  }

  // W2 B-fragments resident in registers (B[k][n] = W2[n][k]).
  short8 w2f[2][4];
  #pragma unroll
  for (int nt = 0; nt < 2; ++nt) {
    int nn = nbase + (nt << 4) + lcol;
    #pragma unroll
    for (int kt = 0; kt < 4; ++kt)
      w2f[nt][kt] = *(const short8*)(w2b + nn * HDIM + (kt << 5) + (quad << 3));
  }
  __syncthreads();

  // ---- W1 pre-pass: c[n] = W1 @ v_n + b1 + b2 via broadcast-A MFMA ----
  // A[m][k] = vn[k] for all m  =>  D[m][n] = c[n] in every acc register.
  float c0, c1;
  {
    floatv4 p0 = {0.f, 0.f, 0.f, 0.f}, p1 = {0.f, 0.f, 0.f, 0.f};
    #pragma unroll
    for (int kt = 0; kt < 4; ++kt) {
      short8 af = *(const short8*)&vnb[(kt << 5) + (quad << 3)];
      short8 bf0 = *(const short8*)(w1b + n0 * HDIM + (kt << 5) + (quad << 3));
      short8 bf1 = *(const short8*)(w1b + n1 * HDIM + (kt << 5) + (quad << 3));
      p0 = __builtin_amdgcn_mfma_f32_16x16x32_bf16(af, bf0, p0, 0, 0, 0);
      p1 = __builtin_amdgcn_mfma_f32_16x16x32_bf16(af, bf1, p1, 0, 0, 0);
    }
    c0 = p0[0] + b1[n0] + b2[n0];
    c1 = p1[0] + b1[n1] + b2[n1];
  }
  const float q0 = qw[n0], q1 = qw[n1];

  // ---- Main: D = hidden @ W2^T + c via MFMA; fused sigmoid + q-dot -> alphaAcc ----
  #pragma unroll
  for (int mt = 0; mt < 4; ++mt) {
    floatv4 a0 = {c0, c0, c0, c0}, a1 = {c1, c1, c1, c1};
    const unsigned short* arow = &hbf[((mt << 4) + lcol) * RS + (quad << 3)];
    #pragma unroll
    for (int kt = 0; kt < 4; ++kt) {
      short8 af = *(const short8*)(arow + (kt << 5));
      a0 = __builtin_amdgcn_mfma_f32_16x16x32_bf16(af, w2f[0][kt], a0, 0, 0, 0);
      a1 = __builtin_amdgcn_mfma_f32_16x16x32_bf16(af, w2f[1][kt], a1, 0, 0, 0);
    }
    // lane holds D[m = quad*4 + r][n0], D[m][n1]
    #pragma unroll
    for (int r = 0; r < 4; ++r) {
      float v = q0 * __builtin_amdgcn_rcpf(1.f + __expf(-a0[r]))
              + q1 * __builtin_amdgcn_rcpf(1.f + __expf(-a1[r]));
      v += __shfl_xor(v, 1, 64);
      v += __shfl_xor(v, 2, 64);
      v += __shfl_xor(v, 4, 64);
      v += __shfl_xor(v, 8, 64);
      if (lcol == 0) atomicAdd(&alphaAcc[(mt << 4) + (quad << 2) + r], v);
    }
  }
  __syncthreads();

  // ---- s_g: vectorized b128 reads, parallel over tokens ----
  {
    int jg = tid & 15, ts = tid >> 4;  // 16 col-groups x 16 token-slots
    float ac[8];
    #pragma unroll
    for (int e = 0; e < 8; ++e) ac[e] = 0.f;
    #pragma unroll
    for (int tt = 0; tt < 4; ++tt) {
      int t = (tt << 4) + ts;
      float al = alphaAcc[t];
      uint4 u = *(const uint4*)&hbf[t * RS + (jg << 3)];
      ac[0] += al * blo(u.x); ac[1] += al * bhi(u.x);
      ac[2] += al * blo(u.y); ac[3] += al * bhi(u.y);
      ac[4] += al * blo(u.z); ac[5] += al * bhi(u.z);
      ac[6] += al * blo(u.w); ac[7] += al * bhi(u.w);
    }
    #pragma unroll
    for (int e = 0; e < 8; ++e) {
      ac[e] += __shfl_xor(ac[e], 16, 64);
      ac[e] += __shfl_xor(ac[e], 32, 64);
    }
    if (quad == 0) {  // lanes 0..15 of each wave hold sums over its 4 token-slots
      float4 s0; s0.x = ac[0]; s0.y = ac[1]; s0.z = ac[2]; s0.w = ac[3];
      float4 s1; s1.x = ac[4]; s1.y = ac[5]; s1.z = ac[6]; s1.w = ac[7];
      *(float4*)&sgpart[wid][(jg << 3)] = s0;
      *(float4*)&sgpart[wid][(jg << 3) + 4] = s1;
    }
  }
  __syncthreads();
  if (tid < HDIM) {
    float s = sgpart[0][tid] + sgpart[1][tid] + sgpart[2][tid] + sgpart[3][tid];
    sgb[tid] = f2bf(s);
  }
  __syncthreads();

  // ---- h_s = [v_n, s_g] @ W3^T + b3 via broadcast-A MFMA ----
  {
    floatv4 o0 = {0.f, 0.f, 0.f, 0.f}, o1 = {0.f, 0.f, 0.f, 0.f};
    #pragma unroll
    for (int kt = 0; kt < 8; ++kt) {
      const unsigned short* src = (kt < 4) ? &vnb[kt << 5] : &sgb[(kt - 4) << 5];
      short8 af = *(const short8*)(src + (quad << 3));
      short8 bf0 = *(const short8*)(w3b + n0 * 256 + (kt << 5) + (quad << 3));
      short8 bf1 = *(const short8*)(w3b + n1 * 256 + (kt << 5) + (quad << 3));
      o0 = __builtin_amdgcn_mfma_f32_16x16x32_bf16(af, bf0, o0, 0, 0, 0);
      o1 = __builtin_amdgcn_mfma_f32_16x16x32_bf16(af, bf1, o1, 0, 0, 0);
    }
    if (quad == 0) {
      out[(size_t)b * HDIM + n0] = o0[0] + b3[n0];
      out[(size_t)b * HDIM + n1] = o1[0] + b3[n1];
    }
  }
}

extern "C" void kernel_launch(void* const* d_in, const int* in_sizes, int n_in,
                              void* d_out, int out_size, void* d_ws, size_t ws_size,
                              hipStream_t stream) {
  const float* intra = (const float*)d_in[0];
  const float* inter = (const float*)d_in[1];
  const float* W1 = (const float*)d_in[2];
  const float* b1 = (const float*)d_in[3];
  const float* W2 = (const float*)d_in[4];
  const float* b2 = (const float*)d_in[5];
  const float* qw = (const float*)d_in[6];
  const float* qb = (const float*)d_in[7];
  const float* W3 = (const float*)d_in[8];
  const float* b3 = (const float*)d_in[9];
  const int* seq = (const int*)d_in[10];
  const int B = in_sizes[10];
  float* out = (float*)d_out;

  char* ws = (char*)d_ws;
  size_t o1 = (((size_t)B * 4) + 255) & ~(size_t)255;  // after offsets
  int* offs = (int*)ws;
  unsigned short* w1b = (unsigned short*)(ws + o1);            // 32 KB
  unsigned short* w2b = (unsigned short*)(ws + o1 + 32768);    // 32 KB
  unsigned short* w3b = (unsigned short*)(ws + o1 + 65536);    // 64 KB

  hipLaunchKernelGGL(prep_kernel, dim3(129), dim3(256), 0, stream,
                     seq, offs, B, W1, W2, W3, w1b, w2b, w3b);
  hipLaunchKernelGGL(session_kernel, dim3(B), dim3(256), 0, stream,
                     intra, inter, w1b, b1, w2b, b2, qw, qb, w3b, b3, seq, offs, out);
}